// Round 4
// baseline (2081.977 us; speedup 1.0000x reference)
//
#include <hip/hip_runtime.h>
#include <stdint.h>

#define BATCH 8
#define K 65536
#define CFEAT 128
#define NPROP 1024
#define M 16            // workgroups per batch
#define T 256           // threads per WG
#define PTS (K / M)     // 4096 points per WG
#define PPT (PTS / T)   // 16 points per thread

// d_out layout (float32): new_xyz (B,N,3) | new_features (B,C,N) | inds (B,N) as float
#define OUT_FEAT (BATCH * NPROP * 3)                         // 24576
#define OUT_INDS (BATCH * NPROP * 3 + BATCH * CFEAT * NPROP) // 1073152

// ws layout: slot[2][BATCH][M] lines, each padded to its OWN 64B cacheline.
// KEY-ONLY protocol (round-3 validated: cut fabric traffic 10x, 2782->1972us):
// word [0] = key { dist_u32 | (0xFFFF-g)<<16 | tag }.
// All spin-path accesses RELAXED agent-scope (acquire emits buffer_inv ->
// chip-wide L2 thrash, round-2 lesson). Exact 16-bit tag + parity
// double-buffer: a WG posts round t only after finishing its poll of round
// t-1, which requires every WG posted t-1, which requires every WG finished
// polling t-2 (the same-parity round) — so overwrite races are impossible.
// Stale 2-deep in-flight poll loads return the OLD tag and are discarded.
#define SLOT_STRIDE 8
#define WS_ULLS (2 * BATCH * M * SLOT_STRIDE)   // 2048 ulls = 16 KB

__global__ __launch_bounds__(256) void fps_init(unsigned long long* ws) {
    int i = blockIdx.x * 256 + threadIdx.x;
    if (i < WS_ULLS) ws[i] = 0ull;   // tag 0 never matches t in [1,1023]
}

// Wave-wide u32 max via DPP (HW-validated rounds 2-3). Max lands in lane 63.
__device__ __forceinline__ unsigned int wave_umax63(unsigned int x) {
    int v = (int)x;
    int t;
    t = __builtin_amdgcn_update_dpp(v, v, 0x111, 0xF, 0xF, false);  // row_shr:1
    v = ((unsigned)t > (unsigned)v) ? t : v;
    t = __builtin_amdgcn_update_dpp(v, v, 0x112, 0xF, 0xF, false);  // row_shr:2
    v = ((unsigned)t > (unsigned)v) ? t : v;
    t = __builtin_amdgcn_update_dpp(v, v, 0x114, 0xF, 0xF, false);  // row_shr:4
    v = ((unsigned)t > (unsigned)v) ? t : v;
    t = __builtin_amdgcn_update_dpp(v, v, 0x118, 0xF, 0xF, false);  // row_shr:8
    v = ((unsigned)t > (unsigned)v) ? t : v;
    t = __builtin_amdgcn_update_dpp(v, v, 0x142, 0xF, 0xF, false);  // row_bcast:15
    v = ((unsigned)t > (unsigned)v) ? t : v;
    t = __builtin_amdgcn_update_dpp(v, v, 0x143, 0xF, 0xF, false);  // row_bcast:31
    v = ((unsigned)t > (unsigned)v) ? t : v;
    return (unsigned int)v;
}

// 16-lane (row 0) u32 max via DPP; max of lanes 0..15 lands in lane 15.
__device__ __forceinline__ unsigned int row16_umax15(unsigned int x) {
    int v = (int)x;
    int t;
    t = __builtin_amdgcn_update_dpp(v, v, 0x111, 0xF, 0xF, false);  // row_shr:1
    v = ((unsigned)t > (unsigned)v) ? t : v;
    t = __builtin_amdgcn_update_dpp(v, v, 0x112, 0xF, 0xF, false);  // row_shr:2
    v = ((unsigned)t > (unsigned)v) ? t : v;
    t = __builtin_amdgcn_update_dpp(v, v, 0x114, 0xF, 0xF, false);  // row_shr:4
    v = ((unsigned)t > (unsigned)v) ? t : v;
    t = __builtin_amdgcn_update_dpp(v, v, 0x118, 0xF, 0xF, false);  // row_shr:8
    v = ((unsigned)t > (unsigned)v) ? t : v;
    return (unsigned int)v;
}

__global__ __launch_bounds__(T) void fps_kernel(const float* __restrict__ xyz,
                                                float* __restrict__ out,
                                                unsigned long long* __restrict__ ws) {
    const int b = blockIdx.x & 7;   // batch's 16 WGs round-robin onto one XCD
    const int w = blockIdx.x >> 3;
    const int tid = threadIdx.x;
    const int lane = tid & 63;
    const float* xb = xyz + (size_t)b * (K * 3);
    const int base = w * PTS;

    __shared__ unsigned long long s_kmax[2];   // parity-indexed cross-wave max
    __shared__ float s_qx, s_qy, s_qz;

    float px[PPT], py[PPT], pz[PPT], dist[PPT];
#pragma unroll
    for (int j = 0; j < PPT; ++j) {
        int l = j * T + tid;
        int g = base + l;
        px[j] = xb[3 * g];
        py[j] = xb[3 * g + 1];
        pz[j] = xb[3 * g + 2];
        dist[j] = 1e10f;
    }
    float qx = xb[0], qy = xb[1], qz = xb[2];
    if (tid == 0) { s_kmax[0] = 0ull; s_kmax[1] = 0ull; }
    if (w == 0 && tid == 0) out[OUT_INDS + b * NPROP] = 0.0f;
    __syncthreads();   // s_kmax init visible

    for (int t = 1; t < NPROP; ++t) {
        // ---- local distance update + per-lane argmax (bit-exact vs numpy:
        // no FMA contraction, (dx2+dy2)+dz2 order, first-max tie-break via
        // strict > over ascending l) ----
        float bestd = -1.0f;
        unsigned int bestl = 0;
#pragma unroll
        for (int j = 0; j < PPT; ++j) {
            float dx = __fsub_rn(px[j], qx);
            float dy = __fsub_rn(py[j], qy);
            float dz = __fsub_rn(pz[j], qz);
            float d = __fadd_rn(__fadd_rn(__fmul_rn(dx, dx), __fmul_rn(dy, dy)),
                                __fmul_rn(dz, dz));
            float nd = fminf(dist[j], d);
            dist[j] = nd;
            unsigned int l = (unsigned int)(j * T + tid);
            bool gt = nd > bestd;
            bestd = gt ? nd : bestd;
            bestl = gt ? l : bestl;
        }
        // ---- wave-level two-phase argmax via DPP (dist >= 0 so float order
        // == u32 bit order; phase2 max(~l) == first-max tie-break) ----
        unsigned int du = __float_as_uint(bestd);
        unsigned int m1 = wave_umax63(du);
        unsigned int maxd = (unsigned int)__builtin_amdgcn_readlane((int)m1, 63);
        unsigned int cand = (du == maxd) ? ~bestl : 0u;
        unsigned int m2 = wave_umax63(cand);

        const int par = t & 1;
        unsigned long long* sgrp = ws + (size_t)((par * BATCH + b) * M) * SLOT_STRIDE;
        const unsigned int tt = (unsigned int)t;

        // ---- cross-wave combine via LDS atomicMax (replaces 4-key scan) ----
        if (lane == 63) {
            unsigned int l = ~m2;                 // wave-winner local index
            unsigned int g = (unsigned int)base + l;
            unsigned long long key = ((unsigned long long)maxd << 32) |
                                     ((unsigned long long)((0xFFFFu - g) & 0xFFFFu) << 16) |
                                     (unsigned long long)tt;
            atomicMax(&s_kmax[par], key);
        }
        __syncthreads();   // S1

        if (tid == 0) {
            unsigned long long kb = s_kmax[par];
            s_kmax[par] = 0ull;                   // consumed; next use is t+2
            __hip_atomic_store(&sgrp[(size_t)w * SLOT_STRIDE], kb,
                               __ATOMIC_RELAXED, __HIP_MEMORY_SCOPE_AGENT);
        }

        // ---- spin-exchange: lanes 0..15 watch one padded key line each.
        // 2-deep software-pipelined poll: sampling period ~ latency/2, which
        // halves both the expected overshoot and the max-of-16-WGs tail. ----
        if (tid < M) {
            unsigned long long* sp = sgrp + (size_t)tid * SLOT_STRIDE;
            unsigned long long a = __hip_atomic_load(sp, __ATOMIC_RELAXED,
                                                     __HIP_MEMORY_SCOPE_AGENT);
            unsigned long long bq = __hip_atomic_load(sp, __ATOMIC_RELAXED,
                                                      __HIP_MEMORY_SCOPE_AGENT);
            unsigned long long k = 0ull;
            bool got = false;
            for (;;) {
                if (!got && (unsigned short)a == (unsigned short)tt) { k = a; got = true; }
                if (__all(got)) break;
                a = __hip_atomic_load(sp, __ATOMIC_RELAXED, __HIP_MEMORY_SCOPE_AGENT);
                if (!got && (unsigned short)bq == (unsigned short)tt) { k = bq; got = true; }
                if (__all(got)) break;
                bq = __hip_atomic_load(sp, __ATOMIC_RELAXED, __HIP_MEMORY_SCOPE_AGENT);
            }
            // ---- speculative per-lane candidate coords (overlap the reduce;
            // xyz is immutable so plain cached loads are safe) ----
            unsigned int gl = 0xFFFFu - (unsigned int)((k >> 16) & 0xFFFFu);
            const float* cp = xb + 3 * (size_t)gl;
            float cxl = cp[0], cyl = cp[1], czl = cp[2];
            // ---- two-phase argmax over 16 keys via DPP ----
            unsigned int hi = (unsigned int)(k >> 32);
            unsigned int lo = (unsigned int)k;
            unsigned int p1 = row16_umax15(hi);
            unsigned int maxk = (unsigned int)__builtin_amdgcn_readlane((int)p1, 15);
            unsigned int c2 = (hi == maxk) ? lo : 0u;   // lo = (0xFFFF-g)<<16 | t
            unsigned int p2 = row16_umax15(c2);
            unsigned int low = (unsigned int)__builtin_amdgcn_readlane((int)p2, 15);
            unsigned int g = 0xFFFFu - (low >> 16);
            int s = (int)(g >> 12);                     // winner WG/slot (PTS=4096)
            int ad = s << 2;
            // pull winner coords from the lane that polled slot s
            float wx = __uint_as_float((unsigned int)__builtin_amdgcn_ds_bpermute(
                ad, (int)__float_as_uint(cxl)));
            float wy = __uint_as_float((unsigned int)__builtin_amdgcn_ds_bpermute(
                ad, (int)__float_as_uint(cyl)));
            float wz = __uint_as_float((unsigned int)__builtin_amdgcn_ds_bpermute(
                ad, (int)__float_as_uint(czl)));
            if (tid == 0) {
                s_qx = wx; s_qy = wy; s_qz = wz;
                if (w == 0) out[OUT_INDS + b * NPROP + t] = (float)g;
            }
        }
        __syncthreads();   // S2
        qx = s_qx; qy = s_qy; qz = s_qz;
    }
}

__global__ __launch_bounds__(256) void gather_kernel(const float* __restrict__ xyz,
                                                     const float* __restrict__ feat,
                                                     float* __restrict__ out) {
    int gid = blockIdx.x * 256 + threadIdx.x;   // covers B*C*N = 1,048,576
    int n = gid & (NPROP - 1);
    int b = gid >> 17;                          // C*N = 2^17
    int c = (gid >> 10) & (CFEAT - 1);
    int ind = (int)out[OUT_INDS + (b << 10) + n];   // float inds, exact < 2^24
    out[OUT_FEAT + gid] = feat[(((size_t)b * CFEAT + c) << 16) + (size_t)ind];
    if (gid < BATCH * NPROP) {
        int b2 = gid >> 10;
        int ind2 = (int)out[OUT_INDS + gid];
        const float* s = xyz + ((size_t)b2 * K + (size_t)ind2) * 3;
        float a0 = s[0], a1 = s[1], a2 = s[2];
        out[gid * 3 + 0] = a0;
        out[gid * 3 + 1] = a1;
        out[gid * 3 + 2] = a2;
    }
}

extern "C" void kernel_launch(void* const* d_in, const int* in_sizes, int n_in,
                              void* d_out, int out_size, void* d_ws, size_t ws_size,
                              hipStream_t stream) {
    const float* xyz = (const float*)d_in[0];
    const float* feat = (const float*)d_in[1];
    float* out = (float*)d_out;
    unsigned long long* ws = (unsigned long long*)d_ws;

    hipLaunchKernelGGL(fps_init, dim3(WS_ULLS / 256), dim3(256), 0, stream, ws);
    hipLaunchKernelGGL(fps_kernel, dim3(BATCH * M), dim3(T), 0, stream,
                       xyz, out, ws);
    hipLaunchKernelGGL(gather_kernel, dim3(BATCH * CFEAT * NPROP / 256), dim3(256),
                       0, stream, xyz, feat, out);
}